// Round 3
// baseline (81.897 us; speedup 1.0000x reference)
//
#include <hip/hip_runtime.h>
#include <math.h>

// Problem constants (from reference)
#define NB   128
#define NC   3
#define NH   384
#define NW   384
#define W4   (NW / 4)             // 96 float4 per row
#define PER_IMG4 (NC * NH * W4)   // 110592 float4 per image
#define NCLS 1000
#define NCLS4 (NCLS / 4)          // 250 float4 per label row
#define XBLOCKS (PER_IMG4 / 256)  // 432 blocks of 256 quads per image

// clang ext vector so __builtin_nontemporal_* accept it
typedef float f4 __attribute__((ext_vector_type(4)));

// Fused kernel:
//  blockIdx.x < XBLOCKS : image select  out = mask ? x[mix] : x  (float4/thread)
//  blockIdx.x == XBLOCKS: label mix     out = lam*l + (1-lam)*l[mix]
//
// Cache policy bet (R3): loads of x are NON-TEMPORAL (don't allocate /
// evict-first), stores are REGULAR. If the 256MB Infinity Cache is
// write-allocate, the 226.5MB output buffer stays L3-resident across the
// timed graph replays -> steady-state HBM traffic = read stream only.
__global__ __launch_bounds__(256) void cutmix_fused_kernel(
    const f4* __restrict__ x,
    const f4* __restrict__ labels,
    const float* __restrict__ lambdaVal,
    const float* __restrict__ startVals,
    const int* __restrict__ mixIdx,
    f4* __restrict__ out_x,
    f4* __restrict__ out_labels)
{
    const int b = blockIdx.y;

    // per-batch cut window, exact f32 semantics of the reference:
    // cut = int(384 * sqrt(1 - lam)); start = int(sv * float(384 - cut))
    const float lam = lambdaVal[b];
    const int   cut = (int)(384.0f * sqrtf(1.0f - lam));
    const int   s   = (int)(startVals[b] * (float)(NH - cut));
    const int   e   = s + cut;
    const int   m   = mixIdx[b];

    if (blockIdx.x == XBLOCKS) {
        // ---- label mix: 250 float4 per batch ----
        const int t = threadIdx.x;
        if (t < NCLS4) {
            const f4 a  = labels[b * NCLS4 + t];
            const f4 mb = labels[m * NCLS4 + t];
            const float il = 1.0f - lam;
            f4 o;
            o.x = lam * a.x + il * mb.x;
            o.y = lam * a.y + il * mb.y;
            o.z = lam * a.z + il * mb.z;
            o.w = lam * a.w + il * mb.w;
            out_labels[b * NCLS4 + t] = o;
        }
        return;
    }

    // ---- image select ----
    const int j   = blockIdx.x * 256 + threadIdx.x;   // [0, PER_IMG4)
    const int rem = j % (NH * W4);
    const int r   = rem / W4;
    const int cq  = rem - r * W4;

    const int base = b * PER_IMG4 + j;

    f4 o;
    if (r < s || r >= e) {
        // row outside cut window: pure copy
        o = __builtin_nontemporal_load(&x[base]);
    } else {
        const int mbase = m * PER_IMG4 + j;
        const int c0    = cq * 4;
        if (c0 >= s && c0 + 4 <= e) {
            o = __builtin_nontemporal_load(&x[mbase]);   // quad fully inside cut
        } else if (c0 + 4 <= s || c0 >= e) {
            o = __builtin_nontemporal_load(&x[base]);    // quad fully outside cut cols
        } else {
            // boundary quad: per-element select (rare)
            const f4 a  = __builtin_nontemporal_load(&x[base]);
            const f4 mm = __builtin_nontemporal_load(&x[mbase]);
            o.x = (c0 + 0 >= s && c0 + 0 < e) ? mm.x : a.x;
            o.y = (c0 + 1 >= s && c0 + 1 < e) ? mm.y : a.y;
            o.z = (c0 + 2 >= s && c0 + 2 < e) ? mm.z : a.z;
            o.w = (c0 + 3 >= s && c0 + 3 < e) ? mm.w : a.w;
        }
    }
    // Regular store: let the output buffer allocate in L3 and stay resident.
    out_x[base] = o;
}

extern "C" void kernel_launch(void* const* d_in, const int* in_sizes, int n_in,
                              void* d_out, int out_size, void* d_ws, size_t ws_size,
                              hipStream_t stream)
{
    const f4*    x         = (const f4*)d_in[0];
    const f4*    labels    = (const f4*)d_in[1];
    const float* lambdaVal = (const float*)d_in[2];
    const float* startVals = (const float*)d_in[3];
    const int*   mixIdx    = (const int*)d_in[4];

    float* out = (float*)d_out;
    f4* out_x      = (f4*)out;                                  // 56,623,104 floats
    f4* out_labels = (f4*)(out + (size_t)NB * NC * NH * NW);    // 128,000 floats

    dim3 grid(XBLOCKS + 1, NB);   // 433 x 128 blocks, 256 threads
    cutmix_fused_kernel<<<grid, 256, 0, stream>>>(
        x, labels, lambdaVal, startVals, mixIdx, out_x, out_labels);
}

// Round 4
// 72.938 us; speedup vs baseline: 1.1228x; 1.1228x over previous
//
#include <hip/hip_runtime.h>
#include <math.h>

// Problem constants (from reference)
#define NB   128
#define NC   3
#define NH   384
#define NW   384
#define W4   (NW / 4)             // 96 float4 per row
#define PER_IMG4 (NC * NH * W4)   // 110592 float4 per image
#define NCLS 1000
#define NCLS4 (NCLS / 4)          // 250 float4 per label row
#define XBLOCKS (PER_IMG4 / 256)  // 432 blocks of 256 quads per image

// clang ext vector so __builtin_nontemporal_store accepts it
typedef float f4 __attribute__((ext_vector_type(4)));

// Fused kernel (R2 configuration — best measured: 73.3 us, 98% of the
// 6.29 TB/s mixed copy ceiling for 453 MB of traffic):
//  blockIdx.x < XBLOCKS : image select  out = mask ? x[mix] : x  (float4/thread)
//  blockIdx.x == XBLOCKS: label mix     out = lam*l + (1-lam)*l[mix]
//
// Cache policy (verified by A/B over R1/R2/R3):
//  - loads REGULAR (nt-loads regressed 73.3 -> 81.9 us: evict-first kills
//    L2/L3 hits on x, including boundary-quad re-reads)
//  - stores NON-TEMPORAL (R1 regular-stores = 85.2 us; keeps the 226 MB
//    output stream from evicting x's partial cache residency)
__global__ __launch_bounds__(256) void cutmix_fused_kernel(
    const f4* __restrict__ x,
    const f4* __restrict__ labels,
    const float* __restrict__ lambdaVal,
    const float* __restrict__ startVals,
    const int* __restrict__ mixIdx,
    f4* __restrict__ out_x,
    f4* __restrict__ out_labels)
{
    const int b = blockIdx.y;

    // per-batch cut window, exact f32 semantics of the reference:
    // cut = int(384 * sqrt(1 - lam)); start = int(sv * float(384 - cut))
    const float lam = lambdaVal[b];
    const int   cut = (int)(384.0f * sqrtf(1.0f - lam));
    const int   s   = (int)(startVals[b] * (float)(NH - cut));
    const int   e   = s + cut;
    const int   m   = mixIdx[b];

    if (blockIdx.x == XBLOCKS) {
        // ---- label mix: 250 float4 per batch ----
        const int t = threadIdx.x;
        if (t < NCLS4) {
            const f4 a  = labels[b * NCLS4 + t];
            const f4 mb = labels[m * NCLS4 + t];
            const float il = 1.0f - lam;
            f4 o;
            o.x = lam * a.x + il * mb.x;
            o.y = lam * a.y + il * mb.y;
            o.z = lam * a.z + il * mb.z;
            o.w = lam * a.w + il * mb.w;
            out_labels[b * NCLS4 + t] = o;
        }
        return;
    }

    // ---- image select ----
    const int j   = blockIdx.x * 256 + threadIdx.x;   // [0, PER_IMG4)
    const int rem = j % (NH * W4);
    const int r   = rem / W4;
    const int cq  = rem - r * W4;

    const int base = b * PER_IMG4 + j;

    f4 o;
    if (r < s || r >= e) {
        // row outside cut window: pure copy
        o = x[base];
    } else {
        const int mbase = m * PER_IMG4 + j;
        const int c0    = cq * 4;
        if (c0 >= s && c0 + 4 <= e) {
            o = x[mbase];                 // quad fully inside cut
        } else if (c0 + 4 <= s || c0 >= e) {
            o = x[base];                  // quad fully outside cut columns
        } else {
            // boundary quad: per-element select (rare)
            const f4 a  = x[base];
            const f4 mm = x[mbase];
            o.x = (c0 + 0 >= s && c0 + 0 < e) ? mm.x : a.x;
            o.y = (c0 + 1 >= s && c0 + 1 < e) ? mm.y : a.y;
            o.z = (c0 + 2 >= s && c0 + 2 < e) ? mm.z : a.z;
            o.w = (c0 + 3 >= s && c0 + 3 < e) ? mm.w : a.w;
        }
    }
    // Non-temporal store: output stream shouldn't pollute L2/L3.
    __builtin_nontemporal_store(o, &out_x[base]);
}

extern "C" void kernel_launch(void* const* d_in, const int* in_sizes, int n_in,
                              void* d_out, int out_size, void* d_ws, size_t ws_size,
                              hipStream_t stream)
{
    const f4*    x         = (const f4*)d_in[0];
    const f4*    labels    = (const f4*)d_in[1];
    const float* lambdaVal = (const float*)d_in[2];
    const float* startVals = (const float*)d_in[3];
    const int*   mixIdx    = (const int*)d_in[4];

    float* out = (float*)d_out;
    f4* out_x      = (f4*)out;                                  // 56,623,104 floats
    f4* out_labels = (f4*)(out + (size_t)NB * NC * NH * NW);    // 128,000 floats

    dim3 grid(XBLOCKS + 1, NB);   // 433 x 128 blocks, 256 threads
    cutmix_fused_kernel<<<grid, 256, 0, stream>>>(
        x, labels, lambdaVal, startVals, mixIdx, out_x, out_labels);
}